// Round 7
// baseline (183.008 us; speedup 1.0000x reference)
//
#include <hip/hip_runtime.h>

typedef unsigned short u16;
typedef __attribute__((ext_vector_type(8))) short short8;
typedef __attribute__((ext_vector_type(4))) float float4v;
typedef __attribute__((ext_vector_type(4))) unsigned short ushort4v;

__device__ __forceinline__ u16 f2bf(float f) {
    unsigned u = __float_as_uint(f);
    u += 0x7FFFu + ((u >> 16) & 1u);   // RNE
    return (u16)(u >> 16);
}
__device__ __forceinline__ float bf2f(u16 u) {
    return __uint_as_float(((unsigned)u) << 16);
}

// ---------------------------------------------------------------------------
// Module .bss intermediates (d_ws proved unreliable in earlier rounds).
// ---------------------------------------------------------------------------
__device__ float g_maxout[4 * 32 * 4096];   // 2 MB fp32, o-major (for lit)
__device__ float g_maxoutT[4 * 4096 * 32];  // 2 MB fp32, p-major (for rescore)
__device__ float g_q[16384];
__device__ float g_qmean[16384];
__device__ float g_lit[128];
__device__ float g_sigfac[16384];
__device__ u16   g_KwP[65536];              // K_w bf16, MFMA-fragment order
__device__ u16   g_KSAwP[16384];            // KSA_w bf16, MFMA-fragment order
__device__ u16   g_Kx[4 * 256 * 16384];     // Kx bf16, 33.5 MB

// Fragment order: each (o-tile, k-step) fragment = 1024 B contiguous,
// element (o,c) at frag*512 + (((c>>3)&3)*16 + (o&15))*8 + (c&7) shorts.
// K_w  [256 o][256 c]: frag = (o>>4)*8 + (c>>5)   (o-tile-major)
// KSA_w [32 o][512 c]: frag = (c>>5)*2 + (o>>4)   (k-step-major)
__global__ __launch_bounds__(256) void prep_kernel(
    const float* __restrict__ Kw, const float* __restrict__ KSAw)
{
    const int idx = blockIdx.x * 256 + threadIdx.x;
    if (idx < 128) g_lit[idx] = 0.f;
    if (idx < 65536) {
        const int o = idx >> 8, c = idx & 255;
        const int fi = ((o >> 4) << 3) + (c >> 5);
        const int ln = (((c >> 3) & 3) << 4) + (o & 15);
        g_KwP[fi * 512 + ln * 8 + (c & 7)] = f2bf(Kw[idx]);
    }
    if (idx < 16384) {
        const int o = idx >> 9, c = idx & 511;
        const int fi = ((c >> 5) << 1) + (o >> 4);
        const int ln = (((c >> 3) & 3) << 4) + (o & 15);
        g_KSAwP[fi * 512 + ln * 8 + (c & 7)] = f2bf(KSAw[idx]);
    }
}

// ---------------------------------------------------------------------------
// Deep conv via MFMA (unchanged from R6): maxout = KSA_w * deep + bias,
// fused qstats + dual maxout/maxoutT write.
// ---------------------------------------------------------------------------
__global__ __launch_bounds__(256) void gemm_deep(
    const float* __restrict__ Bias, const float* __restrict__ X)
{
    __shared__ u16 As[16384];                 // [32 frag][512 shorts]
    const int t = threadIdx.x;
    const int wave = t >> 6, lane = t & 63;
    const int quad = lane >> 4, n16 = lane & 15;
    const int b = blockIdx.y;
    const int p = blockIdx.x * 64 + wave * 16 + n16;
    const float* Xb = X + ((long long)b << 21) + p;

#pragma unroll
    for (int i = 0; i < 8; i++)
        *(short8*)(As + ((i << 8) + t) * 8) = *(const short8*)(g_KSAwP + ((i << 8) + t) * 8);

    float xr[3][8];
#define DXLOAD(dst, kb_) { \
    const float* xp_ = Xb + ((((kb_) << 5) + (quad << 3)) << 12); \
    _Pragma("unroll") for (int j = 0; j < 8; j++) dst[j] = xp_[j << 12]; }

    DXLOAD(xr[0], 0)
    DXLOAD(xr[1], 1)
    DXLOAD(xr[2], 2)

    __syncthreads();

    float4v acc[2];
#pragma unroll
    for (int i = 0; i < 2; i++) acc[i] = (float4v){0.f, 0.f, 0.f, 0.f};

#pragma unroll
    for (int kb = 0; kb < 16; kb++) {
        short8 bfrag;
#pragma unroll
        for (int j = 0; j < 8; j++) bfrag[j] = (short)f2bf(xr[kb % 3][j]);
        if (kb < 13) DXLOAD(xr[(kb + 3) % 3], kb + 3)
#pragma unroll
        for (int ot = 0; ot < 2; ot++) {
            const short8 afrag = *(const short8*)(As + (((kb << 1) + ot) << 9) + lane * 8);
            acc[ot] = __builtin_amdgcn_mfma_f32_16x16x32_bf16(afrag, bfrag, acc[ot], 0, 0, 0);
        }
    }
#undef DXLOAD

    float mx = -3.4e38f, sm = 0.f;
#pragma unroll
    for (int ot = 0; ot < 2; ot++) {
        float4v vv;
#pragma unroll
        for (int r = 0; r < 4; r++) {
            const int o = ot * 16 + quad * 4 + r;
            vv[r] = acc[ot][r] + Bias[o];
            g_maxout[((b * 32 + o) << 12) + p] = vv[r];
            mx = fmaxf(mx, vv[r]);
            sm += vv[r];
        }
        *(float4v*)(g_maxoutT + (((b << 12) + p) << 5) + ot * 16 + quad * 4) = vv;
    }
    mx = fmaxf(mx, __shfl_xor(mx, 16, 64));
    sm += __shfl_xor(sm, 16, 64);
    mx = fmaxf(mx, __shfl_xor(mx, 32, 64));
    sm += __shfl_xor(sm, 32, 64);
    if (quad == 0) {
        g_q[(b << 12) + p] = mx;
        g_qmean[(b << 12) + p] = sm * (1.f / 32.f);
    }
}

// lit[b][l] = (1/4096) * sum_i q[b][i] * flat[b][i*32+l]; 512 blocks (2/CU).
__global__ __launch_bounds__(256) void lit_kernel()
{
    const int b = blockIdx.y;
    const int f0 = blockIdx.x * 1024;
    const int t = threadIdx.x;
    const float* mo = g_maxout + (b << 17);
    const float* qb = g_q + (b << 12);
    float acc = 0.f;
#pragma unroll
    for (int it = 0; it < 4; it++) {
        const int f = f0 + it * 256 + t;
        acc += qb[f >> 5] * mo[f];
    }
    __shared__ float red[256];
    red[t] = acc;
    __syncthreads();
    if (t < 32) {
        float s = 0.f;
#pragma unroll
        for (int k = 0; k < 8; k++) s += red[t + k * 32];
        atomicAdd(&g_lit[b * 32 + t], s * (1.f / 4096.f));
    }
}

// re_score -> out tail (fp32); sigfac = 1 + sigmoid(re).
__global__ __launch_bounds__(128) void rescore_kernel(float* __restrict__ out_re)
{
    const int idx = blockIdx.x * 128 + threadIdx.x;  // 16384
    const int b = idx >> 12;
    const float4v* mt = (const float4v*)(g_maxoutT + (idx << 5));
    const float4v* lb = (const float4v*)(g_lit + b * 32);
    float r = 0.f;
#pragma unroll
    for (int j = 0; j < 8; j++) {
        const float4v m4 = mt[j];
        const float4v l4 = lb[j];
        r += m4[0] * l4[0] + m4[1] * l4[1] + m4[2] * l4[2] + m4[3] * l4[3];
    }
    out_re[idx] = r;
    g_sigfac[idx] = 1.f + 1.f / (1.f + __expf(-r));
}

// ---------------------------------------------------------------------------
// Shallow conv v8: Kx[b][o][p] = sum_c K_w[o][c]*shallow[b][c][p] + bias.
// THE structural fix: every prior variant read B as 8 scalar fp32 loads at
// 64 KB stride per K-step (channel-gather) -- uncoalesced AND on the MFMA
// dependency chain. Now the block's whole B-tile (64 p x 256 c) is staged
// ONCE with float4 loads along p (1 KB/inst), cvt'd to bf16 into a 32 KB
// [p][c] LDS tile, XOR-swizzled (colU16 ^= (p&7)<<3) so the K-loop's
// ds_read_b128 channel-gathers are conflict-free. K-loop: NO global B, NO
// barriers -- 8 steps of {4 A-frags from L2-hot g_KwP (reg dbuf) + 4 bfrag
// LDS reads + 16 MFMA}, square 64p x 64o wave tile. Waves slip freely;
// ~4-5 blocks/CU of TLP hides all latency even if the compiler de-pipelines.
// ---------------------------------------------------------------------------
__global__ __launch_bounds__(256) void gemm_kx(
    const float* __restrict__ Bias, const float* __restrict__ X)
{
    __shared__ u16 Bs[16384];                 // 32 KB: [64 p][256 c] swizzled
    const int t = threadIdx.x;
    const int wave = t >> 6, lane = t & 63;
    const int quad = lane >> 4, n16 = lane & 15;
    const int b = blockIdx.y;
    const int p0 = blockIdx.x * 64;
    const float* Xb = X + ((long long)b << 22);

    // A: wave owns o in [wave*64, wave*64+64) -> frags i=0..3 per k-step.
    const u16* Ap = g_KwP + wave * 16384 + lane * 8;  // + i*4096 + kb*512

    short8 areg[2][4];
#pragma unroll
    for (int i = 0; i < 4; i++) areg[0][i] = *(const short8*)(Ap + i * 4096);

    // Stage B: pass g covers c in [g*64,(g+1)*64) x all 64 p.
    // Thread: c0 = g*64+(t>>4)*4, pl0 = (t&15)*4; 4 float4 loads along p,
    // transpose in regs, 4 ds_write_b64 at [pl][c0^((pl&7)<<3)].
    {
        const int c0b = (t >> 4) << 2;
        const int pl0 = (t & 15) << 2;
#pragma unroll
        for (int g = 0; g < 4; g++) {
            const int c0 = (g << 6) + c0b;
            float4v v[4];
#pragma unroll
            for (int cr = 0; cr < 4; cr++)
                v[cr] = *(const float4v*)(Xb + ((long long)(c0 + cr) << 14) + p0 + pl0);
#pragma unroll
            for (int pj = 0; pj < 4; pj++) {
                const int pl = pl0 + pj;
                ushort4v w;
#pragma unroll
                for (int cr = 0; cr < 4; cr++) w[cr] = f2bf(v[cr][pj]);
                *(ushort4v*)(Bs + (pl << 8) + (c0 ^ ((pl & 7) << 3))) = w;
            }
        }
    }

    float4v acc[4][4];   // [pg][i]
#pragma unroll
    for (int i = 0; i < 4; i++)
#pragma unroll
        for (int j = 0; j < 4; j++) acc[i][j] = (float4v){0.f, 0.f, 0.f, 0.f};

    __syncthreads();

#pragma unroll
    for (int kb = 0; kb < 8; kb++) {
        const int cr = kb & 1;
        if (kb < 7) {
#pragma unroll
            for (int i = 0; i < 4; i++)
                areg[cr ^ 1][i] = *(const short8*)(Ap + i * 4096 + (kb + 1) * 512);
        }
        short8 bf[4];
#pragma unroll
        for (int pg = 0; pg < 4; pg++) {
            const int pl = (pg << 4) + n16;
            const int c0 = (kb << 5) + (quad << 3);
            bf[pg] = *(const short8*)(Bs + (pl << 8) + (c0 ^ ((pl & 7) << 3)));
        }
#pragma unroll
        for (int pg = 0; pg < 4; pg++)
#pragma unroll
            for (int i = 0; i < 4; i++)
                acc[pg][i] = __builtin_amdgcn_mfma_f32_16x16x32_bf16(
                    bf[pg], areg[cr][i], acc[pg][i], 0, 0, 0);
    }

    // D[p][o]: row(p_local) = pg*16 + quad*4 + r, col(o) = wave*64+i*16+n16
    // (swapped operands; mapping refcheck-proven in R2)
    u16* kxb = g_Kx + (((long long)b << 8) << 14);
#pragma unroll
    for (int i = 0; i < 4; i++) {
        const int o = wave * 64 + i * 16 + n16;
        const float bo = Bias[o];
        u16* orow = kxb + ((long long)o << 14) + p0 + (quad << 2);
#pragma unroll
        for (int pg = 0; pg < 4; pg++) {
            ushort4v w;
#pragma unroll
            for (int r = 0; r < 4; r++) w[r] = f2bf(acc[pg][i][r] + bo);
            *(ushort4v*)(orow + (pg << 4)) = w;
        }
    }
}

// ---------------------------------------------------------------------------
// Windowed softmax attention (unchanged from R6).
// ---------------------------------------------------------------------------
__global__ __launch_bounds__(256) void att_window(float* __restrict__ out)
{
    __shared__ u16 tile[8][9][132];            // 18.6 KB
    const int t = threadIdx.x;
    const int o0 = blockIdx.y << 3, b = blockIdx.z;
    const int y0 = (blockIdx.x << 3) - 1;
    const u16* kxb = g_Kx + (((long long)b << 8) << 14);

    if (t < 72) tile[t / 9][t % 9][64] = 0;    // x=-1 pad per (o,row)
#pragma unroll
    for (int k = 0; k < 18; k++) {
        const int e = (k << 8) + t;            // 0..4607 = 72 rows x 64 pairs
        const int row = e >> 6, pr = e & 63;
        const int oi = row / 9, r = row - oi * 9;
        const int y = y0 + r;
        unsigned v = 0;
        if (y >= 0 && y < 128)
            v = *(const unsigned*)(kxb + (((long long)(o0 + oi)) << 14) + (y << 7) + (pr << 1));
        tile[oi][r][pr] = (u16)(v & 0xffffu);          // even x = 2*pr
        tile[oi][r][65 + pr] = (u16)(v >> 16);         // odd  x = 2*pr+1
    }
    __syncthreads();

    const int p = (blockIdx.x << 8) + t;       // 0..4095
    const int pw = t & 63;
    const int rl = (t >> 6) << 1;
    const float m = g_qmean[(b << 12) + p];
    const float sf = g_sigfac[(b << 12) + p];

#pragma unroll
    for (int oi = 0; oi < 8; oi++) {
        float v[9];
#pragma unroll
        for (int ki = 0; ki < 3; ++ki) {
            v[ki * 3 + 0] = bf2f(tile[oi][rl + ki][64 + pw]);   // x = 2pw-1
            v[ki * 3 + 1] = bf2f(tile[oi][rl + ki][pw]);        // x = 2pw
            v[ki * 3 + 2] = bf2f(tile[oi][rl + ki][65 + pw]);   // x = 2pw+1
        }
        float mx = -3.4e38f;
#pragma unroll
        for (int k = 0; k < 9; ++k) mx = fmaxf(mx, m * v[k]);
        float s = 0.f, a = 0.f;
#pragma unroll
        for (int k = 0; k < 9; ++k) {
            const float e = __expf(m * v[k] - mx);
            s += e;
            a += e * v[k];
        }
        out[((((long long)b << 8) + o0 + oi) << 12) + p] = (a / s) * sf;
    }
}

extern "C" void kernel_launch(void* const* d_in, const int* in_sizes, int n_in,
                              void* d_out, int out_size, void* d_ws, size_t ws_size,
                              hipStream_t stream) {
    const float *shallow = 0, *deep = 0, *K_w = 0, *K_b = 0, *KSA_w = 0, *KSA_b = 0;
    for (int i = 0; i < n_in; ++i) {
        switch (in_sizes[i]) {
            case 16777216: shallow = (const float*)d_in[i]; break;
            case 8388608:  deep    = (const float*)d_in[i]; break;
            case 65536:    K_w     = (const float*)d_in[i]; break;
            case 256:      K_b     = (const float*)d_in[i]; break;
            case 16384:    KSA_w   = (const float*)d_in[i]; break;
            case 32:       KSA_b   = (const float*)d_in[i]; break;
        }
    }
    float* out = (float*)d_out;   // FP32: 4194304 att + 16384 re_score

    // 0) zero lit + pack both weight matrices into MFMA-fragment order
    prep_kernel<<<320, 256, 0, stream>>>(K_w, KSA_w);
    // 1) deep conv + fused channel max/mean + transposed maxout
    gemm_deep<<<dim3(64, 4), 256, 0, stream>>>(KSA_b, deep);
    // 2) lit (channel-scrambled, /hw), 512 blocks
    lit_kernel<<<dim3(128, 4), 256, 0, stream>>>();
    // 3) re_score (fp32 -> out tail) + sigmoid factor
    rescore_kernel<<<128, 128, 0, stream>>>(out + 4194304);
    // 4) shallow conv v8: coalesced B-tile staging + barrier-free K-loop
    gemm_kx<<<dim3(256, 4), 256, 0, stream>>>(K_b, shallow);
    // 5) windowed softmax attention, 8 channels per block
    att_window<<<dim3(16, 32, 4), 256, 0, stream>>>(out);
}

// Round 8
// 179.836 us; speedup vs baseline: 1.0176x; 1.0176x over previous
//
#include <hip/hip_runtime.h>

typedef unsigned short u16;
typedef __attribute__((ext_vector_type(8))) short short8;
typedef __attribute__((ext_vector_type(4))) float float4v;
typedef __attribute__((ext_vector_type(4))) unsigned short ushort4v;

__device__ __forceinline__ u16 f2bf(float f) {
    unsigned u = __float_as_uint(f);
    u += 0x7FFFu + ((u >> 16) & 1u);   // RNE
    return (u16)(u >> 16);
}
__device__ __forceinline__ float bf2f(u16 u) {
    return __uint_as_float(((unsigned)u) << 16);
}

// ---------------------------------------------------------------------------
// Module .bss intermediates (d_ws proved unreliable in earlier rounds).
// ---------------------------------------------------------------------------
__device__ float g_maxout[4 * 32 * 4096];   // 2 MB fp32, o-major (for lit)
__device__ float g_maxoutT[4 * 4096 * 32];  // 2 MB fp32, p-major (for rescore)
__device__ float g_q[16384];
__device__ float g_qmean[16384];
__device__ float g_lit[128];
__device__ float g_sigfac[16384];
__device__ u16   g_KwP[65536];              // K_w bf16, MFMA-fragment order
__device__ u16   g_KSAwP[16384];            // KSA_w bf16, MFMA-fragment order
__device__ u16   g_Kx[4 * 256 * 16384];     // Kx bf16, 33.5 MB

// Fragment order: each (o-tile, k-step) fragment = 1024 B contiguous,
// element (o,c) at frag*512 + (((c>>3)&3)*16 + (o&15))*8 + (c&7) shorts.
// K_w  [256 o][256 c]: frag = (o>>4)*8 + (c>>5)   (o-tile-major)
// KSA_w [32 o][512 c]: frag = (c>>5)*2 + (o>>4)   (k-step-major)
__global__ __launch_bounds__(256) void prep_kernel(
    const float* __restrict__ Kw, const float* __restrict__ KSAw)
{
    const int idx = blockIdx.x * 256 + threadIdx.x;
    if (idx < 128) g_lit[idx] = 0.f;
    if (idx < 65536) {
        const int o = idx >> 8, c = idx & 255;
        const int fi = ((o >> 4) << 3) + (c >> 5);
        const int ln = (((c >> 3) & 3) << 4) + (o & 15);
        g_KwP[fi * 512 + ln * 8 + (c & 7)] = f2bf(Kw[idx]);
    }
    if (idx < 16384) {
        const int o = idx >> 9, c = idx & 511;
        const int fi = ((c >> 5) << 1) + (o >> 4);
        const int ln = (((c >> 3) & 3) << 4) + (o & 15);
        g_KSAwP[fi * 512 + ln * 8 + (c & 7)] = f2bf(KSAw[idx]);
    }
}

// ---------------------------------------------------------------------------
// Deep conv via MFMA (unchanged from R6): maxout = KSA_w * deep + bias,
// fused qstats + dual maxout/maxoutT write.
// ---------------------------------------------------------------------------
__global__ __launch_bounds__(256) void gemm_deep(
    const float* __restrict__ Bias, const float* __restrict__ X)
{
    __shared__ u16 As[16384];                 // [32 frag][512 shorts]
    const int t = threadIdx.x;
    const int wave = t >> 6, lane = t & 63;
    const int quad = lane >> 4, n16 = lane & 15;
    const int b = blockIdx.y;
    const int p = blockIdx.x * 64 + wave * 16 + n16;
    const float* Xb = X + ((long long)b << 21) + p;

#pragma unroll
    for (int i = 0; i < 8; i++)
        *(short8*)(As + ((i << 8) + t) * 8) = *(const short8*)(g_KSAwP + ((i << 8) + t) * 8);

    float xr[3][8];
#define DXLOAD(dst, kb_) { \
    const float* xp_ = Xb + ((((kb_) << 5) + (quad << 3)) << 12); \
    _Pragma("unroll") for (int j = 0; j < 8; j++) dst[j] = xp_[j << 12]; }

    DXLOAD(xr[0], 0)
    DXLOAD(xr[1], 1)
    DXLOAD(xr[2], 2)

    __syncthreads();

    float4v acc[2];
#pragma unroll
    for (int i = 0; i < 2; i++) acc[i] = (float4v){0.f, 0.f, 0.f, 0.f};

#pragma unroll
    for (int kb = 0; kb < 16; kb++) {
        short8 bfrag;
#pragma unroll
        for (int j = 0; j < 8; j++) bfrag[j] = (short)f2bf(xr[kb % 3][j]);
        if (kb < 13) DXLOAD(xr[(kb + 3) % 3], kb + 3)
#pragma unroll
        for (int ot = 0; ot < 2; ot++) {
            const short8 afrag = *(const short8*)(As + (((kb << 1) + ot) << 9) + lane * 8);
            acc[ot] = __builtin_amdgcn_mfma_f32_16x16x32_bf16(afrag, bfrag, acc[ot], 0, 0, 0);
        }
    }
#undef DXLOAD

    float mx = -3.4e38f, sm = 0.f;
#pragma unroll
    for (int ot = 0; ot < 2; ot++) {
        float4v vv;
#pragma unroll
        for (int r = 0; r < 4; r++) {
            const int o = ot * 16 + quad * 4 + r;
            vv[r] = acc[ot][r] + Bias[o];
            g_maxout[((b * 32 + o) << 12) + p] = vv[r];
            mx = fmaxf(mx, vv[r]);
            sm += vv[r];
        }
        *(float4v*)(g_maxoutT + (((b << 12) + p) << 5) + ot * 16 + quad * 4) = vv;
    }
    mx = fmaxf(mx, __shfl_xor(mx, 16, 64));
    sm += __shfl_xor(sm, 16, 64);
    mx = fmaxf(mx, __shfl_xor(mx, 32, 64));
    sm += __shfl_xor(sm, 32, 64);
    if (quad == 0) {
        g_q[(b << 12) + p] = mx;
        g_qmean[(b << 12) + p] = sm * (1.f / 32.f);
    }
}

// lit[b][l] = (1/4096) * sum_i q[b][i] * flat[b][i*32+l]; 512 blocks (2/CU).
__global__ __launch_bounds__(256) void lit_kernel()
{
    const int b = blockIdx.y;
    const int f0 = blockIdx.x * 1024;
    const int t = threadIdx.x;
    const float* mo = g_maxout + (b << 17);
    const float* qb = g_q + (b << 12);
    float acc = 0.f;
#pragma unroll
    for (int it = 0; it < 4; it++) {
        const int f = f0 + it * 256 + t;
        acc += qb[f >> 5] * mo[f];
    }
    __shared__ float red[256];
    red[t] = acc;
    __syncthreads();
    if (t < 32) {
        float s = 0.f;
#pragma unroll
        for (int k = 0; k < 8; k++) s += red[t + k * 32];
        atomicAdd(&g_lit[b * 32 + t], s * (1.f / 4096.f));
    }
}

// re_score -> out tail (fp32); sigfac = 1 + sigmoid(re).
__global__ __launch_bounds__(128) void rescore_kernel(float* __restrict__ out_re)
{
    const int idx = blockIdx.x * 128 + threadIdx.x;  // 16384
    const int b = idx >> 12;
    const float4v* mt = (const float4v*)(g_maxoutT + (idx << 5));
    const float4v* lb = (const float4v*)(g_lit + b * 32);
    float r = 0.f;
#pragma unroll
    for (int j = 0; j < 8; j++) {
        const float4v m4 = mt[j];
        const float4v l4 = lb[j];
        r += m4[0] * l4[0] + m4[1] * l4[1] + m4[2] * l4[2] + m4[3] * l4[3];
    }
    out_re[idx] = r;
    g_sigfac[idx] = 1.f + 1.f / (1.f + __expf(-r));
}

// ---------------------------------------------------------------------------
// Shallow conv v9: identical read side / K-loop to v8 (coalesced B-tile
// staging, barrier-free K-loop, A from L2-hot g_KwP). ONE change: the
// epilogue. v0-v8 all scattered each 64-lane Kx store across 16 o-rows in
// 32-B segments -- WRITE_SIZE was a constant 41 MB vs 33.5 logical (+22%
// partial-sector RMW) in every round. v9 routes acc through a [256 o][72]
// LDS C-tile, then stores cooperatively: each inst = 8 rows x 128 B fully
// contiguous -> full-line dirty in L2, clean HBM bursts.
// ---------------------------------------------------------------------------
__global__ __launch_bounds__(256) void gemm_kx(
    const float* __restrict__ Bias, const float* __restrict__ X)
{
    __shared__ u16 S[18432];                  // 36 KB: Bs [64][256] then C [256][72]
    const int t = threadIdx.x;
    const int wave = t >> 6, lane = t & 63;
    const int quad = lane >> 4, n16 = lane & 15;
    const int b = blockIdx.y;
    const int p0 = blockIdx.x * 64;
    const float* Xb = X + ((long long)b << 22);

    // A: wave owns o in [wave*64, wave*64+64) -> frags i=0..3 per k-step.
    const u16* Ap = g_KwP + wave * 16384 + lane * 8;  // + i*4096 + kb*512

    short8 areg[2][4];
#pragma unroll
    for (int i = 0; i < 4; i++) areg[0][i] = *(const short8*)(Ap + i * 4096);

    // Stage B: pass g covers c in [g*64,(g+1)*64) x all 64 p.
    {
        const int c0b = (t >> 4) << 2;
        const int pl0 = (t & 15) << 2;
#pragma unroll
        for (int g = 0; g < 4; g++) {
            const int c0 = (g << 6) + c0b;
            float4v v[4];
#pragma unroll
            for (int cr = 0; cr < 4; cr++)
                v[cr] = *(const float4v*)(Xb + ((long long)(c0 + cr) << 14) + p0 + pl0);
#pragma unroll
            for (int pj = 0; pj < 4; pj++) {
                const int pl = pl0 + pj;
                ushort4v w;
#pragma unroll
                for (int cr = 0; cr < 4; cr++) w[cr] = f2bf(v[cr][pj]);
                *(ushort4v*)(S + (pl << 8) + (c0 ^ ((pl & 7) << 3))) = w;
            }
        }
    }

    float4v acc[4][4];   // [pg][i]
#pragma unroll
    for (int i = 0; i < 4; i++)
#pragma unroll
        for (int j = 0; j < 4; j++) acc[i][j] = (float4v){0.f, 0.f, 0.f, 0.f};

    __syncthreads();

#pragma unroll
    for (int kb = 0; kb < 8; kb++) {
        const int cr = kb & 1;
        if (kb < 7) {
#pragma unroll
            for (int i = 0; i < 4; i++)
                areg[cr ^ 1][i] = *(const short8*)(Ap + i * 4096 + (kb + 1) * 512);
        }
        short8 bf[4];
#pragma unroll
        for (int pg = 0; pg < 4; pg++) {
            const int pl = (pg << 4) + n16;
            const int c0 = (kb << 5) + (quad << 3);
            bf[pg] = *(const short8*)(S + (pl << 8) + (c0 ^ ((pl & 7) << 3)));
        }
#pragma unroll
        for (int pg = 0; pg < 4; pg++)
#pragma unroll
            for (int i = 0; i < 4; i++)
                acc[pg][i] = __builtin_amdgcn_mfma_f32_16x16x32_bf16(
                    bf[pg], areg[cr][i], acc[pg][i], 0, 0, 0);
    }

    // Epilogue v9: acc -> LDS C-tile [o_local 256][72 u16] -> coalesced store.
    // acc mapping (refcheck-proven R2/R7): p_local = pg*16+quad*4+r,
    // o = wave*64 + i*16 + n16.
    __syncthreads();                           // waves done reading B-tile
#pragma unroll
    for (int i = 0; i < 4; i++) {
        const int o = wave * 64 + i * 16 + n16;
        const float bo = Bias[o];
#pragma unroll
        for (int pg = 0; pg < 4; pg++) {
            ushort4v w;
#pragma unroll
            for (int r = 0; r < 4; r++) w[r] = f2bf(acc[pg][i][r] + bo);
            *(ushort4v*)(S + o * 72 + (pg << 4) + (quad << 2)) = w;
        }
    }
    __syncthreads();

    // Store: pass k covers rows [k*32, k*32+32); lane group (t>>3) = row,
    // (t&7) = 16-B chunk -> each inst writes 8 rows x 128 B contiguous.
    u16* kxb = g_Kx + (((long long)b << 8) << 14) + p0;
    const int srow = t >> 3, sc = (t & 7) << 3;
#pragma unroll
    for (int k = 0; k < 8; k++) {
        const int row = (k << 5) + srow;
        const short8 v = *(const short8*)(S + row * 72 + sc);
        *(short8*)(kxb + ((long long)row << 14) + sc) = v;
    }
}

// ---------------------------------------------------------------------------
// Windowed softmax attention (unchanged from R6).
// ---------------------------------------------------------------------------
__global__ __launch_bounds__(256) void att_window(float* __restrict__ out)
{
    __shared__ u16 tile[8][9][132];            // 18.6 KB
    const int t = threadIdx.x;
    const int o0 = blockIdx.y << 3, b = blockIdx.z;
    const int y0 = (blockIdx.x << 3) - 1;
    const u16* kxb = g_Kx + (((long long)b << 8) << 14);

    if (t < 72) tile[t / 9][t % 9][64] = 0;    // x=-1 pad per (o,row)
#pragma unroll
    for (int k = 0; k < 18; k++) {
        const int e = (k << 8) + t;            // 0..4607 = 72 rows x 64 pairs
        const int row = e >> 6, pr = e & 63;
        const int oi = row / 9, r = row - oi * 9;
        const int y = y0 + r;
        unsigned v = 0;
        if (y >= 0 && y < 128)
            v = *(const unsigned*)(kxb + (((long long)(o0 + oi)) << 14) + (y << 7) + (pr << 1));
        tile[oi][r][pr] = (u16)(v & 0xffffu);          // even x = 2*pr
        tile[oi][r][65 + pr] = (u16)(v >> 16);         // odd  x = 2*pr+1
    }
    __syncthreads();

    const int p = (blockIdx.x << 8) + t;       // 0..4095
    const int pw = t & 63;
    const int rl = (t >> 6) << 1;
    const float m = g_qmean[(b << 12) + p];
    const float sf = g_sigfac[(b << 12) + p];

#pragma unroll
    for (int oi = 0; oi < 8; oi++) {
        float v[9];
#pragma unroll
        for (int ki = 0; ki < 3; ++ki) {
            v[ki * 3 + 0] = bf2f(tile[oi][rl + ki][64 + pw]);   // x = 2pw-1
            v[ki * 3 + 1] = bf2f(tile[oi][rl + ki][pw]);        // x = 2pw
            v[ki * 3 + 2] = bf2f(tile[oi][rl + ki][65 + pw]);   // x = 2pw+1
        }
        float mx = -3.4e38f;
#pragma unroll
        for (int k = 0; k < 9; ++k) mx = fmaxf(mx, m * v[k]);
        float s = 0.f, a = 0.f;
#pragma unroll
        for (int k = 0; k < 9; ++k) {
            const float e = __expf(m * v[k] - mx);
            s += e;
            a += e * v[k];
        }
        out[((((long long)b << 8) + o0 + oi) << 12) + p] = (a / s) * sf;
    }
}

extern "C" void kernel_launch(void* const* d_in, const int* in_sizes, int n_in,
                              void* d_out, int out_size, void* d_ws, size_t ws_size,
                              hipStream_t stream) {
    const float *shallow = 0, *deep = 0, *K_w = 0, *K_b = 0, *KSA_w = 0, *KSA_b = 0;
    for (int i = 0; i < n_in; ++i) {
        switch (in_sizes[i]) {
            case 16777216: shallow = (const float*)d_in[i]; break;
            case 8388608:  deep    = (const float*)d_in[i]; break;
            case 65536:    K_w     = (const float*)d_in[i]; break;
            case 256:      K_b     = (const float*)d_in[i]; break;
            case 16384:    KSA_w   = (const float*)d_in[i]; break;
            case 32:       KSA_b   = (const float*)d_in[i]; break;
        }
    }
    float* out = (float*)d_out;   // FP32: 4194304 att + 16384 re_score

    // 0) zero lit + pack both weight matrices into MFMA-fragment order
    prep_kernel<<<320, 256, 0, stream>>>(K_w, KSA_w);
    // 1) deep conv + fused channel max/mean + transposed maxout
    gemm_deep<<<dim3(64, 4), 256, 0, stream>>>(KSA_b, deep);
    // 2) lit (channel-scrambled, /hw), 512 blocks
    lit_kernel<<<dim3(128, 4), 256, 0, stream>>>();
    // 3) re_score (fp32 -> out tail) + sigmoid factor
    rescore_kernel<<<128, 128, 0, stream>>>(out + 4194304);
    // 4) shallow conv v9: v8 read side + LDS-transposed coalesced Kx store
    gemm_kx<<<dim3(256, 4), 256, 0, stream>>>(K_b, shallow);
    // 5) windowed softmax attention, 8 channels per block
    att_window<<<dim3(16, 32, 4), 256, 0, stream>>>(out);
}